// Round 6
// baseline (656.421 us; speedup 1.0000x reference)
//
#include <hip/hip_runtime.h>
#include <hip/hip_bf16.h>

#define NUM_HEADS 16
#define DM 1024
#define DEPTH 64
#define BB 4
#define SS 1024
#define SL 1023            // S-1
#define M_ROWS (BB*SL)     // 4092

typedef __attribute__((ext_vector_type(8))) short short8;
typedef __attribute__((ext_vector_type(4))) float floatx4;

__device__ inline unsigned short f2bf(float f) {
  __hip_bfloat16 hb = __float2bfloat16(f);
  return *reinterpret_cast<unsigned short*>(&hb);
}
__device__ inline short8 ld_frag(const unsigned short* p) {
  return *reinterpret_cast<const short8*>(p);
}

// XOR granule swizzle: 16B granules within a 128B row; involution.
#define SWZ(row, g) (((g) ^ ((row) & 7)))

// async global->LDS, 16 B per lane (wave-uniform base + lane*16 dest)
#define GLDS(g, l) __builtin_amdgcn_global_load_lds( \
    (const __attribute__((address_space(1))) void*)(g), \
    (__attribute__((address_space(3))) void*)(l), 16, 0, 0)

// ---------------- prep kernels ----------------------------------------------
__global__ __launch_bounds__(256) void f32_to_bf16_vec(
    const float* __restrict__ in, unsigned short* __restrict__ out, int n8)
{
  int i = blockIdx.x * 256 + threadIdx.x;
  if (i >= n8) return;
  const float4 f0 = ((const float4*)in)[(size_t)i * 2];
  const float4 f1 = ((const float4*)in)[(size_t)i * 2 + 1];
  unsigned short t[8];
  t[0]=f2bf(f0.x); t[1]=f2bf(f0.y); t[2]=f2bf(f0.z); t[3]=f2bf(f0.w);
  t[4]=f2bf(f1.x); t[5]=f2bf(f1.y); t[6]=f2bf(f1.z); t[7]=f2bf(f1.w);
  ((uint4*)out)[i] = *(uint4*)t;
}

// q/k (b, SS, DM) fp32 -> compact bf16 (b, SL, DM), taking rows rowoff..rowoff+SL-1
__global__ __launch_bounds__(256) void conv_rows_bf16(
    const float* __restrict__ in, unsigned short* __restrict__ out, int rowoff)
{
  int i = blockIdx.x * 256 + threadIdx.x;          // 8-elem group id
  const int n8 = (M_ROWS * DM) / 8;                // 523776
  if (i >= n8) return;
  int row = i >> 7;                                // DM/8 = 128 groups per row
  int g = i & 127;
  int b = row / SL, r = row - b * SL;
  const float* src = in + ((size_t)b * SS + r + rowoff) * DM + g * 8;
  const float4 f0 = ((const float4*)src)[0];
  const float4 f1 = ((const float4*)src)[1];
  unsigned short t[8];
  t[0]=f2bf(f0.x); t[1]=f2bf(f0.y); t[2]=f2bf(f0.z); t[3]=f2bf(f0.w);
  t[4]=f2bf(f1.x); t[5]=f2bf(f1.y); t[6]=f2bf(f1.z); t[7]=f2bf(f1.w);
  *(uint4*)(out + (size_t)row * DM + g * 8) = *(uint4*)t;
}

// W[1024][1024] fp32 -> WT[1024][1024] bf16 with WT[n][k] = W[k][n]
__global__ __launch_bounds__(256) void transpose_to_bf16(
    const float* __restrict__ W, unsigned short* __restrict__ WT)
{
  __shared__ unsigned short tile[64][72];
  const int tid = threadIdx.x;
  const int k0 = blockIdx.y * 64, n0 = blockIdx.x * 64;
  {
    const int kl = tid >> 2, nc = (tid & 3) * 16;
    const float* src = W + (size_t)(k0 + kl) * DM + n0 + nc;
    #pragma unroll
    for (int j = 0; j < 16; j += 4) {
      float4 f = *(const float4*)(src + j);
      tile[nc + j + 0][kl] = f2bf(f.x);
      tile[nc + j + 1][kl] = f2bf(f.y);
      tile[nc + j + 2][kl] = f2bf(f.z);
      tile[nc + j + 3][kl] = f2bf(f.w);
    }
  }
  __syncthreads();
  {
    const int nl = tid >> 2, kc = (tid & 3) * 16;
    unsigned short tmp[16];
    #pragma unroll
    for (int j = 0; j < 16; j++) tmp[j] = tile[nl][kc + j];
    unsigned short* dst = WT + (size_t)(n0 + nl) * DM + k0 + kc;
    *(uint4*)&dst[0] = *(uint4*)&tmp[0];
    *(uint4*)&dst[8] = *(uint4*)&tmp[8];
  }
}

// VV[b][key][h*64+d] (bf16) -> VvT[((b*16+h)*64+d)][0..1023] (bf16, key-major rows)
// key column 1023 zero-filled.
__global__ __launch_bounds__(256) void transpose_v(
    const unsigned short* __restrict__ VV, unsigned short* __restrict__ VvT)
{
  __shared__ unsigned short tile[64][72];
  const int kt = blockIdx.x, h = blockIdx.y, b = blockIdx.z;
  const int tid = threadIdx.x;
  {
    const int kr = tid >> 2, c = (tid & 3) * 16;
    const int kj = kt * 64 + kr;
    unsigned short tmp[16];
    if (kj < SL) {
      const unsigned short* s = VV + ((size_t)b * SL + kj) * DM + h * DEPTH + c;
      *(uint4*)&tmp[0] = *(const uint4*)s;
      *(uint4*)&tmp[8] = *(const uint4*)(s + 8);
    } else {
      #pragma unroll
      for (int j = 0; j < 16; j++) tmp[j] = 0;
    }
    #pragma unroll
    for (int j = 0; j < 16; j++) tile[c + j][kr] = tmp[j];
  }
  __syncthreads();
  {
    const int d = tid >> 2, k16 = (tid & 3) * 16;
    unsigned short tmp[16];
    #pragma unroll
    for (int j = 0; j < 16; j++) tmp[j] = tile[d][k16 + j];
    unsigned short* dst = VvT + (((size_t)(b * NUM_HEADS + h)) * DEPTH + d) * 1024 + kt * 64 + k16;
    *(uint4*)&dst[0] = *(uint4*)&tmp[0];
    *(uint4*)&dst[8] = *(uint4*)&tmp[8];
  }
}

// ---------------- GEMM: C[M x 1024] = A * BT^T + bias -----------------------
template <bool OUT_BF16>
__global__ __launch_bounds__(256) void gemm_bt(
    const unsigned short* __restrict__ A,   // [M][DM] bf16
    const unsigned short* __restrict__ BT,  // [DM][DM] bf16 (n-major)
    const float* __restrict__ bias,
    void* __restrict__ Cv, int M)
{
  constexpr int BM = 64, BN = 128, BK = 64;
  __shared__ __align__(16) unsigned short As[3][BM * BK];   // 3 x 8 KB
  __shared__ __align__(16) unsigned short Bs[3][BN * BK];   // 3 x 16 KB

  const int tid = threadIdx.x;
  const int w = tid >> 6, lane = tid & 63, q4 = lane >> 4, l16 = lane & 15;
  const int wm = w >> 1, wn = w & 1;

  // XCD swizzle: 512 blocks, 512%8==0 -> chunked bijective remap
  const int flat = blockIdx.y * gridDim.x + blockIdx.x;
  const int nf = (flat & 7) * ((int)(gridDim.x * gridDim.y) >> 3) + (flat >> 3);
  const int rb = (nf >> 3) * BM;          // 64 row-tiles
  const int cb = (nf & 7) * BN;           // 8 col-tiles

  const int wbase = __builtin_amdgcn_readfirstlane(w * 512);

  const int srow = tid >> 3;                   // 0..31
  const int lg   = (tid & 7) ^ (srow & 7);     // logical granule (inverse swizzle)
  int ar0 = rb + srow;       if (ar0 >= M) ar0 = M - 1;
  int ar1 = rb + 32 + srow;  if (ar1 >= M) ar1 = M - 1;
  const unsigned short* a_src0 = A + (size_t)ar0 * DM + lg * 8;
  const unsigned short* a_src1 = A + (size_t)ar1 * DM + lg * 8;
  const unsigned short* b_src0 = BT + (size_t)(cb      + srow) * DM + lg * 8;
  const unsigned short* b_src1 = BT + (size_t)(cb + 32 + srow) * DM + lg * 8;
  const unsigned short* b_src2 = BT + (size_t)(cb + 64 + srow) * DM + lg * 8;
  const unsigned short* b_src3 = BT + (size_t)(cb + 96 + srow) * DM + lg * 8;

  auto stage = [&](int t, unsigned short* Ab, unsigned short* Bb) {
    const int kn = t * BK;
    GLDS(a_src0 + kn, Ab + wbase);
    GLDS(a_src1 + kn, Ab + 2048 + wbase);
    GLDS(b_src0 + kn, Bb + wbase);
    GLDS(b_src1 + kn, Bb + 2048 + wbase);
    GLDS(b_src2 + kn, Bb + 4096 + wbase);
    GLDS(b_src3 + kn, Bb + 6144 + wbase);
  };

  int aoff[2][2], boff[4][2];
  #pragma unroll
  for (int i = 0; i < 2; i++)
    #pragma unroll
    for (int hf = 0; hf < 2; hf++) {
      int r = wm * 32 + i * 16 + l16;
      aoff[i][hf] = r * BK + SWZ(r, q4 + 4 * hf) * 8;
    }
  #pragma unroll
  for (int j = 0; j < 4; j++)
    #pragma unroll
    for (int hf = 0; hf < 2; hf++) {
      int r = wn * 64 + j * 16 + l16;
      boff[j][hf] = r * BK + SWZ(r, q4 + 4 * hf) * 8;
    }

  floatx4 acc[2][4];
  #pragma unroll
  for (int i = 0; i < 2; i++)
    #pragma unroll
    for (int j = 0; j < 4; j++) acc[i][j] = (floatx4){0.f,0.f,0.f,0.f};

  stage(0, As[0], Bs[0]);
  stage(1, As[1], Bs[1]);
  stage(2, As[2], Bs[2]);

  int cur = 0;
  constexpr int NT = DM / BK;   // 16
  for (int t = 0; t < NT; ++t) {
    if (t < NT - 2)       asm volatile("s_waitcnt vmcnt(12)" ::: "memory");
    else if (t == NT - 2) asm volatile("s_waitcnt vmcnt(6)"  ::: "memory");
    else                  asm volatile("s_waitcnt vmcnt(0)"  ::: "memory");
    __builtin_amdgcn_sched_barrier(0);
    __builtin_amdgcn_s_barrier();
    __builtin_amdgcn_sched_barrier(0);

    unsigned short* Ab = As[cur];
    unsigned short* Bb = Bs[cur];
    short8 af[2][2], bfr[4][2];
    #pragma unroll
    for (int hf = 0; hf < 2; hf++) {
      af[0][hf] = ld_frag(Ab + aoff[0][hf]);
      af[1][hf] = ld_frag(Ab + aoff[1][hf]);
      bfr[0][hf] = ld_frag(Bb + boff[0][hf]);
      bfr[1][hf] = ld_frag(Bb + boff[1][hf]);
      bfr[2][hf] = ld_frag(Bb + boff[2][hf]);
      bfr[3][hf] = ld_frag(Bb + boff[3][hf]);
    }
    asm volatile("s_waitcnt lgkmcnt(0)" ::: "memory");
    __builtin_amdgcn_sched_barrier(0);
    __builtin_amdgcn_s_barrier();
    __builtin_amdgcn_sched_barrier(0);

    if (t + 3 < NT) stage(t + 3, Ab, Bb);

    #pragma unroll
    for (int hf = 0; hf < 2; hf++) {
      acc[0][0] = __builtin_amdgcn_mfma_f32_16x16x32_bf16(af[0][hf], bfr[0][hf], acc[0][0], 0,0,0);
      acc[0][1] = __builtin_amdgcn_mfma_f32_16x16x32_bf16(af[0][hf], bfr[1][hf], acc[0][1], 0,0,0);
      acc[0][2] = __builtin_amdgcn_mfma_f32_16x16x32_bf16(af[0][hf], bfr[2][hf], acc[0][2], 0,0,0);
      acc[0][3] = __builtin_amdgcn_mfma_f32_16x16x32_bf16(af[0][hf], bfr[3][hf], acc[0][3], 0,0,0);
      acc[1][0] = __builtin_amdgcn_mfma_f32_16x16x32_bf16(af[1][hf], bfr[0][hf], acc[1][0], 0,0,0);
      acc[1][1] = __builtin_amdgcn_mfma_f32_16x16x32_bf16(af[1][hf], bfr[1][hf], acc[1][1], 0,0,0);
      acc[1][2] = __builtin_amdgcn_mfma_f32_16x16x32_bf16(af[1][hf], bfr[2][hf], acc[1][2], 0,0,0);
      acc[1][3] = __builtin_amdgcn_mfma_f32_16x16x32_bf16(af[1][hf], bfr[3][hf], acc[1][3], 0,0,0);
    }
    cur = (cur == 2) ? 0 : cur + 1;
  }

  #pragma unroll
  for (int j = 0; j < 4; j++) {
    int col = cb + wn * 64 + j * 16 + l16;
    float bb = bias[col];
    #pragma unroll
    for (int i = 0; i < 2; i++) {
      #pragma unroll
      for (int r = 0; r < 4; r++) {
        int m = rb + wm * 32 + i * 16 + q4 * 4 + r;
        if (m < M) {
          float val = acc[i][j][r] + bb;
          if (OUT_BF16) ((unsigned short*)Cv)[(size_t)m * DM + col] = f2bf(val);
          else __builtin_nontemporal_store(val, &((float*)Cv)[(size_t)m * DM + col]);
        }
      }
    }
  }
}

// ---------------- Attention, prep path (bf16 Q/K compact 1023-row, VvT) -----
__global__ __launch_bounds__(256) void attn_bf(
    const unsigned short* __restrict__ Qbf,   // (b, SL, DM) = q rows 1..1023
    const unsigned short* __restrict__ Kbf,   // (b, SL, DM) = k rows 0..1022
    const float* __restrict__ Mask, const unsigned short* __restrict__ VvT,
    float* __restrict__ Att, unsigned short* __restrict__ Out2)
{
  const int h = blockIdx.x, qt = blockIdx.y, b = blockIdx.z;
  const int tid = threadIdx.x;
  const int w = tid >> 6, lane = tid & 63, q4 = lane >> 4, l16 = lane & 15;
  const int qi0 = qt * 64;
  const int qb = w * 16;

  __shared__ unsigned short qsh[64][72];     // [q][d]
  __shared__ unsigned short ksh[64][72];     // [key][d]
  __shared__ unsigned short vshT[64][72];    // [d][key]
  __shared__ unsigned short psh[4][16][72];  // per-wave P [q][key]

  {
    const int qr = tid >> 2, d0 = (tid & 3) * 16;
    const int qi = qi0 + qr;
    if (qi < SL) {
      const unsigned short* s = Qbf + ((size_t)b * SL + qi) * DM + h * DEPTH + d0;
      *(uint4*)&qsh[qr][d0]     = *(const uint4*)s;
      *(uint4*)&qsh[qr][d0 + 8] = *(const uint4*)(s + 8);
    } else {
      uint4 z = {0,0,0,0};
      *(uint4*)&qsh[qr][d0] = z;
      *(uint4*)&qsh[qr][d0 + 8] = z;
    }
  }

  auto stageK = [&](int kt) {
    const int kr = tid >> 2, d0 = (tid & 3) * 16;
    const int kj = kt * 64 + kr;
    if (kj < SL) {
      const unsigned short* s = Kbf + ((size_t)b * SL + kj) * DM + h * DEPTH + d0;
      *(uint4*)&ksh[kr][d0]     = *(const uint4*)s;
      *(uint4*)&ksh[kr][d0 + 8] = *(const uint4*)(s + 8);
    } else {
      uint4 z = {0,0,0,0};
      *(uint4*)&ksh[kr][d0] = z;
      *(uint4*)&ksh[kr][d0 + 8] = z;
    }
  };
  auto stageV = [&](int kt) {
    const int d = tid >> 2, c = (tid & 3) * 16;
    const unsigned short* s = VvT + (((size_t)(b * NUM_HEADS + h)) * DEPTH + d) * 1024 + kt * 64 + c;
    *(uint4*)&vshT[d][c]     = *(const uint4*)s;
    *(uint4*)&vshT[d][c + 8] = *(const uint4*)(s + 8);
  };

  __syncthreads();

  const short8 qf0 = ld_frag(&qsh[qb + l16][q4 * 8]);
  const short8 qf1 = ld_frag(&qsh[qb + l16][32 + q4 * 8]);
  const int qi_b = qi0 + qb + q4 * 4;

  // ---- pass 1: rowsums ----
  float rsv[4] = {0.f, 0.f, 0.f, 0.f};
  for (int kt = 0; kt < 16; kt++) {
    __syncthreads();
    stageK(kt);
    __syncthreads();
    #pragma unroll
    for (int nt = 0; nt < 4; nt++) {
      floatx4 s = (floatx4){0.f,0.f,0.f,0.f};
      s = __builtin_amdgcn_mfma_f32_16x16x32_bf16(
            qf0, ld_frag(&ksh[nt*16 + l16][q4*8]), s, 0,0,0);
      s = __builtin_amdgcn_mfma_f32_16x16x32_bf16(
            qf1, ld_frag(&ksh[nt*16 + l16][32 + q4*8]), s, 0,0,0);
      int kj = kt * 64 + nt * 16 + l16;
      bool kv = kj < SL;
      const float* mp = Mask + ((size_t)b * SL + qi_b) * SL + kj;
      #pragma unroll
      for (int r = 0; r < 4; r++) {
        int qi = qi_b + r;
        float mval = (kv && qi < SL) ? mp[(size_t)r * SL] : 0.f;
        float sv = fmaxf(s[r] * 0.125f, 0.f) + mval * (-1e9f);
        float p = kv ? __expf(sv) : 0.f;
        rsv[r] += p;
      }
    }
  }
  #pragma unroll
  for (int r = 0; r < 4; r++) {
    #pragma unroll
    for (int off = 1; off < 16; off <<= 1) rsv[r] += __shfl_xor(rsv[r], off, 64);
  }
  float inv[4];
  #pragma unroll
  for (int r = 0; r < 4; r++) inv[r] = 1.f / rsv[r];

  // ---- pass 2: att + PV ----
  floatx4 oacc[4];
  #pragma unroll
  for (int i = 0; i < 4; i++) oacc[i] = (floatx4){0.f,0.f,0.f,0.f};

  for (int kt = 0; kt < 16; kt++) {
    __syncthreads();
    stageK(kt);
    stageV(kt);
    __syncthreads();
    #pragma unroll
    for (int nt = 0; nt < 4; nt++) {
      floatx4 s = (floatx4){0.f,0.f,0.f,0.f};
      s = __builtin_amdgcn_mfma_f32_16x16x32_bf16(
            qf0, ld_frag(&ksh[nt*16 + l16][q4*8]), s, 0,0,0);
      s = __builtin_amdgcn_mfma_f32_16x16x32_bf16(
            qf1, ld_frag(&ksh[nt*16 + l16][32 + q4*8]), s, 0,0,0);
      int kj = kt * 64 + nt * 16 + l16;
      bool kv = kj < SL;
      const float* mp = Mask + ((size_t)b * SL + qi_b) * SL + kj;
      #pragma unroll
      for (int r = 0; r < 4; r++) {
        int qi = qi_b + r;
        bool qv = qi < SL;
        float mval = (kv && qv) ? mp[(size_t)r * SL] : 0.f;
        float sv = fmaxf(s[r] * 0.125f, 0.f) + mval * (-1e9f);
        float p = kv ? __expf(sv) : 0.f;
        float pn = p * inv[r];
        if (kv && qv)
          Att[(((size_t)(b * NUM_HEADS + h)) * SL + qi) * SL + kj] = pn;
        psh[w][q4 * 4 + r][nt * 16 + l16] = f2bf(pn);
      }
    }
    short8 pa0 = ld_frag(&psh[w][l16][q4 * 8]);
    short8 pa1 = ld_frag(&psh[w][l16][32 + q4 * 8]);
    #pragma unroll
    for (int nt2 = 0; nt2 < 4; nt2++) {
      oacc[nt2] = __builtin_amdgcn_mfma_f32_16x16x32_bf16(
                    pa0, ld_frag(&vshT[nt2*16 + l16][q4*8]), oacc[nt2], 0,0,0);
      oacc[nt2] = __builtin_amdgcn_mfma_f32_16x16x32_bf16(
                    pa1, ld_frag(&vshT[nt2*16 + l16][32 + q4*8]), oacc[nt2], 0,0,0);
    }
  }

  #pragma unroll
  for (int nt2 = 0; nt2 < 4; nt2++) {
    #pragma unroll
    for (int r = 0; r < 4; r++) {
      int qi = qi0 + qb + q4 * 4 + r;
      if (qi < SL)
        Out2[((size_t)b * SL + qi) * DM + h * DEPTH + nt2 * 16 + l16] = f2bf(oacc[nt2][r]);
    }
  }
}

// ---------------- Attention, fallback path (R4: fp32 Q/K, vv gather) --------
__global__ __launch_bounds__(256) void attn_f32(
    const float* __restrict__ Q, const float* __restrict__ Kg,
    const float* __restrict__ Mask, const unsigned short* __restrict__ VV,
    float* __restrict__ Att, unsigned short* __restrict__ Out2)
{
  const int h = blockIdx.x, qt = blockIdx.y, b = blockIdx.z;
  const int tid = threadIdx.x;
  const int w = tid >> 6, lane = tid & 63, q4 = lane >> 4, l16 = lane & 15;
  const int qi0 = qt * 64;
  const int qb = w * 16;

  __shared__ unsigned short qsh[64][72];
  __shared__ unsigned short ksh[64][72];
  __shared__ unsigned short vshT[64][72];
  __shared__ unsigned short psh[4][16][72];

  {
    int qr = tid >> 2, d0 = (tid & 3) * 16;
    int qi = qi0 + qr;
    unsigned short tmp[16];
    if (qi < SL) {
      const float* src = Q + ((size_t)b * SS + qi + 1) * DM + h * DEPTH + d0;
      #pragma unroll
      for (int j = 0; j < 16; j += 4) {
        float4 f = *(const float4*)(src + j);
        tmp[j+0]=f2bf(f.x); tmp[j+1]=f2bf(f.y); tmp[j+2]=f2bf(f.z); tmp[j+3]=f2bf(f.w);
      }
    } else {
      #pragma unroll
      for (int j = 0; j < 16; j++) tmp[j] = 0;
    }
    *(uint4*)&qsh[qr][d0]     = *(uint4*)&tmp[0];
    *(uint4*)&qsh[qr][d0 + 8] = *(uint4*)&tmp[8];
  }

  auto stageK = [&](int kt) {
    int kr = tid >> 2, d0 = (tid & 3) * 16;
    int kj = kt * 64 + kr;
    unsigned short tmp[16];
    if (kj < SL) {
      const float* src = Kg + ((size_t)b * SS + kj) * DM + h * DEPTH + d0;
      #pragma unroll
      for (int j = 0; j < 16; j += 4) {
        float4 f = *(const float4*)(src + j);
        tmp[j+0]=f2bf(f.x); tmp[j+1]=f2bf(f.y); tmp[j+2]=f2bf(f.z); tmp[j+3]=f2bf(f.w);
      }
    } else {
      #pragma unroll
      for (int j = 0; j < 16; j++) tmp[j] = 0;
    }
    *(uint4*)&ksh[kr][d0]     = *(uint4*)&tmp[0];
    *(uint4*)&ksh[kr][d0 + 8] = *(uint4*)&tmp[8];
  };

  auto stageV = [&](int kt) {
    int d = tid & 63, k16 = (tid >> 6) * 16;
    unsigned short tmp[16];
    #pragma unroll
    for (int j = 0; j < 16; j++) {
      int kj = kt * 64 + k16 + j;
      tmp[j] = (kj < SL) ? VV[((size_t)b * SL + kj) * DM + h * DEPTH + d] : (unsigned short)0;
    }
    *(uint4*)&vshT[d][k16]     = *(uint4*)&tmp[0];
    *(uint4*)&vshT[d][k16 + 8] = *(uint4*)&tmp[8];
  };

  __syncthreads();

  float rsv[4] = {0.f, 0.f, 0.f, 0.f};
  for (int kt = 0; kt < 16; kt++) {
    __syncthreads();
    stageK(kt);
    __syncthreads();
    #pragma unroll
    for (int nt = 0; nt < 4; nt++) {
      floatx4 s = (floatx4){0.f,0.f,0.f,0.f};
      s = __builtin_amdgcn_mfma_f32_16x16x32_bf16(
            ld_frag(&qsh[qb + l16][q4*8]), ld_frag(&ksh[nt*16 + l16][q4*8]), s, 0,0,0);
      s = __builtin_amdgcn_mfma_f32_16x16x32_bf16(
            ld_frag(&qsh[qb + l16][32 + q4*8]), ld_frag(&ksh[nt*16 + l16][32 + q4*8]), s, 0,0,0);
      int kj = kt * 64 + nt * 16 + l16;
      bool kv = kj < SL;
      int qi_b = qi0 + qb + q4 * 4;
      const float* mp = Mask + ((size_t)b * SL + qi_b) * SL + kj;
      #pragma unroll
      for (int r = 0; r < 4; r++) {
        int qi = qi_b + r;
        float mval = (kv && qi < SL) ? mp[(size_t)r * SL] : 0.f;
        float sv = fmaxf(s[r] * 0.125f, 0.f) + mval * (-1e9f);
        float p = kv ? __expf(sv) : 0.f;
        rsv[r] += p;
      }
    }
  }
  #pragma unroll
  for (int r = 0; r < 4; r++) {
    #pragma unroll
    for (int off = 1; off < 16; off <<= 1) rsv[r] += __shfl_xor(rsv[r], off, 64);
  }
  float inv[4];
  #pragma unroll
  for (int r = 0; r < 4; r++) inv[r] = 1.f / rsv[r];

  floatx4 oacc[4];
  #pragma unroll
  for (int i = 0; i < 4; i++) oacc[i] = (floatx4){0.f,0.f,0.f,0.f};

  for (int kt = 0; kt < 16; kt++) {
    __syncthreads();
    stageK(kt);
    stageV(kt);
    __syncthreads();
    #pragma unroll
    for (int nt = 0; nt < 4; nt++) {
      floatx4 s = (floatx4){0.f,0.f,0.f,0.f};
      s = __builtin_amdgcn_mfma_f32_16x16x32_bf16(
            ld_frag(&qsh[qb + l16][q4*8]), ld_frag(&ksh[nt*16 + l16][q4*8]), s, 0,0,0);
      s = __builtin_amdgcn_mfma_f32_16x16x32_bf16(
            ld_frag(&qsh[qb + l16][32 + q4*8]), ld_frag(&ksh[nt*16 + l16][32 + q4*8]), s, 0,0,0);
      int kj = kt * 64 + nt * 16 + l16;
      bool kv = kj < SL;
      int qi_b = qi0 + qb + q4 * 4;
      const float* mp = Mask + ((size_t)b * SL + qi_b) * SL + kj;
      #pragma unroll
      for (int r = 0; r < 4; r++) {
        int qi = qi_b + r;
        bool qv = qi < SL;
        float mval = (kv && qv) ? mp[(size_t)r * SL] : 0.f;
        float sv = fmaxf(s[r] * 0.125f, 0.f) + mval * (-1e9f);
        float p = kv ? __expf(sv) : 0.f;
        float pn = p * inv[r];
        if (kv && qv)
          Att[(((size_t)(b * NUM_HEADS + h)) * SL + qi) * SL + kj] = pn;
        psh[w][q4 * 4 + r][nt * 16 + l16] = f2bf(pn);
      }
    }
    short8 pa0 = ld_frag(&psh[w][l16][q4 * 8]);
    short8 pa1 = ld_frag(&psh[w][l16][32 + q4 * 8]);
    #pragma unroll
    for (int nt2 = 0; nt2 < 4; nt2++) {
      oacc[nt2] = __builtin_amdgcn_mfma_f32_16x16x32_bf16(
                    pa0, ld_frag(&vshT[nt2*16 + l16][q4*8]), oacc[nt2], 0,0,0);
      oacc[nt2] = __builtin_amdgcn_mfma_f32_16x16x32_bf16(
                    pa1, ld_frag(&vshT[nt2*16 + l16][32 + q4*8]), oacc[nt2], 0,0,0);
    }
  }

  #pragma unroll
  for (int nt2 = 0; nt2 < 4; nt2++) {
    #pragma unroll
    for (int r = 0; r < 4; r++) {
      int qi = qi0 + qb + q4 * 4 + r;
      if (qi < SL)
        Out2[((size_t)b * SL + qi) * DM + h * DEPTH + nt2 * 16 + l16] = f2bf(oacc[nt2][r]);
    }
  }
}

extern "C" void kernel_launch(void* const* d_in, const int* in_sizes, int n_in,
                              void* d_out, int out_size, void* d_ws, size_t ws_size,
                              hipStream_t stream) {
  const float* v    = (const float*)d_in[0];
  const float* k    = (const float*)d_in[1];
  const float* q    = (const float*)d_in[2];
  const float* mask = (const float*)d_in[3];
  const float* Wv   = (const float*)d_in[4];
  const float* bv   = (const float*)d_in[5];
  const float* Wd   = (const float*)d_in[6];
  const float* bd   = (const float*)d_in[7];

  float* out = (float*)d_out;                                  // (4,1023,1024) fp32
  float* att = out + (size_t)M_ROWS * DM;                      // (4,16,1023,1023) fp32
  unsigned short* vv   = (unsigned short*)d_ws;                // bf16 (4,1023,1024)
  unsigned short* out2 = vv + (size_t)M_ROWS * DM;             // bf16 (4,1023,1024)

  // scratch consumed BEFORE attn may live in the att region:
  unsigned short* WvT = (unsigned short*)att;                  // bf16 [1024][1024]
  unsigned short* vbf = WvT + (size_t)DM * DM;                 // bf16 (4,1023,1024)
  // vv is dead after its last consumer -> reuse for WdT:
  unsigned short* WdT = vv;                                    // bf16 [1024][1024]

  const size_t N = (size_t)M_ROWS * DM;                        // 4,190,208 u16
  const size_t NV = (size_t)BB * NUM_HEADS * DEPTH * 1024;     // 4,194,304 u16
  const size_t need_full = 2 * (2 * N + 2 * N + NV) / 2;       // bytes: (vv+out2+qbf+kbf+VvT)*2
  const size_t full_bytes = (2 * N + 2 * N + NV) * 2;          // 41,910,272 B
  const size_t mid_bytes  = (2 * N + NV) * 2;                  // 25,149,440 B
  (void)need_full;

  const int n8v = (int)(N / 8);

  // common: v -> bf16, Wv^T, gemm1 (vv = v@Wv+bv, bf16)
  f32_to_bf16_vec<<<dim3((n8v + 255) / 256), 256, 0, stream>>>(v, vbf, n8v);
  transpose_to_bf16<<<dim3(16, 16), 256, 0, stream>>>(Wv, WvT);
  gemm_bt<true><<<dim3(DM/128, (M_ROWS+63)/64), 256, 0, stream>>>(vbf, WvT, bv, (void*)vv, M_ROWS);

  if (ws_size >= full_bytes) {
    // Path A: qbf/kbf/VvT all in workspace
    unsigned short* qbf = out2 + N;
    unsigned short* kbf = qbf + N;
    unsigned short* VvT = kbf + N;
    conv_rows_bf16<<<dim3((n8v + 255) / 256), 256, 0, stream>>>(q, qbf, 1);
    conv_rows_bf16<<<dim3((n8v + 255) / 256), 256, 0, stream>>>(k, kbf, 0);
    transpose_v<<<dim3(16, NUM_HEADS, BB), 256, 0, stream>>>(vv, VvT);
    attn_bf<<<dim3(NUM_HEADS, 16, BB), 256, 0, stream>>>(qbf, kbf, mask, VvT, att, out2);
  } else if (ws_size >= mid_bytes) {
    // Path B: qbf/kbf in the out region (dead until final gemm), VvT in ws
    unsigned short* qbf = (unsigned short*)out;                // 2N u16 = out region exactly
    unsigned short* kbf = qbf + N;
    unsigned short* VvT = out2 + N;
    conv_rows_bf16<<<dim3((n8v + 255) / 256), 256, 0, stream>>>(q, qbf, 1);
    conv_rows_bf16<<<dim3((n8v + 255) / 256), 256, 0, stream>>>(k, kbf, 0);
    transpose_v<<<dim3(16, NUM_HEADS, BB), 256, 0, stream>>>(vv, VvT);
    attn_bf<<<dim3(NUM_HEADS, 16, BB), 256, 0, stream>>>(qbf, kbf, mask, VvT, att, out2);
  } else {
    // Path C: proven R4 fallback
    attn_f32<<<dim3(NUM_HEADS, 16, BB), 256, 0, stream>>>(q, k, mask, vv, att, out2);
  }

  transpose_to_bf16<<<dim3(16, 16), 256, 0, stream>>>(Wd, WdT);
  gemm_bt<false><<<dim3(DM/128, (M_ROWS+63)/64), 256, 0, stream>>>(out2, WdT, bd, (void*)out, M_ROWS);
}